// Round 2
// baseline (264.194 us; speedup 1.0000x reference)
//
#include <hip/hip_runtime.h>
#include <hip/hip_bf16.h>
#include <math.h>

#define T_SEQ 1024
#define HIDD 2880
#define NH   64
#define NKVH 8
#define GQ   8
#define HD   64
#define WIN  128
#define QKV_N 5120     // NH*HD + 2*NKVH*HD
#define QDIM  4096     // NH*HD
#define KOFF  4096
#define VOFF  4608
#define NPAD_OUT 3072  // HIDD padded to 12*256 tiles (256-wide N tiling)
#define RMS_EPS 1e-5f
#define Z1 3
#define KS1 960
#define Z2 5
#define KS2 832        // 4 slices of 832 + 1 slice of 768
#define P1SZ (T_SEQ * QKV_N)   // elems per GEMM1 partial slice
#define P2SZ (T_SEQ * HIDD)    // elems per GEMM2 partial slice

typedef __attribute__((ext_vector_type(8))) short short8;
typedef __attribute__((ext_vector_type(4))) short s16x4;
typedef __attribute__((ext_vector_type(4))) float floatx4;

__device__ __forceinline__ float bf2f(unsigned short u) {
    unsigned int x = ((unsigned int)u) << 16;
    float f; __builtin_memcpy(&f, &x, 4); return f;
}
__device__ __forceinline__ unsigned short f2bf(float f) {
    unsigned int x; __builtin_memcpy(&x, &f, 4);
    unsigned int r = (x + 0x7fffu + ((x >> 16) & 1u)) >> 16;
    return (unsigned short)r;
}
__device__ __forceinline__ void glds16(const unsigned short* g, unsigned short* l) {
    __builtin_amdgcn_global_load_lds(
        (const __attribute__((address_space(1))) void*)g,
        (__attribute__((address_space(3))) void*)l, 16, 0, 0);
}

// ---------------- prep: transposes + rmsnorm + rope table (fused) ------------
// Transpose tiles are TALL in K so the transposed (column) writes are long
// bursts: w_qkv 320x64 -> 640B writes, w_out 256x64 -> 512B writes.
__global__ __launch_bounds__(256) void prep_kernel(
    const float* __restrict__ w_qkv, const float* __restrict__ w_out,
    const float* __restrict__ hidden, const float* __restrict__ norm_scale,
    const int* __restrict__ positions,
    unsigned short* __restrict__ bqkvT, unsigned short* __restrict__ boutT,
    unsigned short* __restrict__ xn,
    float* __restrict__ tabc, float* __restrict__ tabs)
{
    __shared__ unsigned short tile[320 * 66];   // 42,240 B
    __shared__ float red[4];
    int blk = blockIdx.x;
    int t = threadIdx.x;

    if (blk < 720) {
        // ---- w_qkv [2880][5120] -> bqkvT [5120][2880], 320x64 tiles ----
        int bx = blk % 80, by = blk / 80;       // by 0..8
        int r0 = by * 320, c0 = bx * 64;
        int rrow = t >> 4, rcol = (t & 15) * 4;
#pragma unroll
        for (int p = 0; p < 20; ++p) {
            int row = p * 16 + rrow;
            float4 v = *(const float4*)&w_qkv[(size_t)(r0 + row) * QKV_N + c0 + rcol];
            unsigned int w0 = (unsigned)f2bf(v.x) | ((unsigned)f2bf(v.y) << 16);
            unsigned int w1 = (unsigned)f2bf(v.z) | ((unsigned)f2bf(v.w) << 16);
            *(unsigned int*)&tile[row * 66 + rcol]     = w0;
            *(unsigned int*)&tile[row * 66 + rcol + 2] = w1;
        }
        __syncthreads();
        int col = t >> 2, seg = t & 3;
        unsigned short* dst = &bqkvT[(size_t)(c0 + col) * HIDD + r0 + seg * 80];
#pragma unroll
        for (int p = 0; p < 10; ++p) {
            unsigned short vb[8];
#pragma unroll
            for (int j = 0; j < 8; ++j) vb[j] = tile[(seg * 80 + p * 8 + j) * 66 + col];
            *(uint4*)(dst + p * 8) = *(uint4*)vb;
        }
    } else if (blk < 1488) {
        // ---- w_out [4096][2880] -> boutT [3072][4096], 256x64 tiles ----
        int r = blk - 720;
        int bx = r % 48, by = r / 48;           // by 0..15; bx>=45 is zero pad
        int r0 = by * 256, c0 = bx * 64;
        bool inr = (c0 < HIDD);
        int rrow = t >> 4, rcol = (t & 15) * 4;
#pragma unroll
        for (int p = 0; p < 16; ++p) {
            int row = p * 16 + rrow;
            float4 v = inr ? *(const float4*)&w_out[(size_t)(r0 + row) * HIDD + c0 + rcol]
                           : make_float4(0.f, 0.f, 0.f, 0.f);
            unsigned int w0 = (unsigned)f2bf(v.x) | ((unsigned)f2bf(v.y) << 16);
            unsigned int w1 = (unsigned)f2bf(v.z) | ((unsigned)f2bf(v.w) << 16);
            *(unsigned int*)&tile[row * 66 + rcol]     = w0;
            *(unsigned int*)&tile[row * 66 + rcol + 2] = w1;
        }
        __syncthreads();
        int col = t >> 2, seg = t & 3;
        unsigned short* dst = &boutT[(size_t)(c0 + col) * QDIM + r0 + seg * 64];
#pragma unroll
        for (int p = 0; p < 8; ++p) {
            unsigned short vb[8];
#pragma unroll
            for (int j = 0; j < 8; ++j) vb[j] = tile[(seg * 64 + p * 8 + j) * 66 + col];
            *(uint4*)(dst + p * 8) = *(uint4*)vb;
        }
    } else if (blk < 2512) {
        int row = blk - 1488;
        const float4* hr4 = (const float4*)(hidden + (size_t)row * HIDD);
        const float4* sc4 = (const float4*)norm_scale;
        float ss = 0.f;
        for (int i = t; i < HIDD / 4; i += 256) {
            float4 v = hr4[i];
            ss += v.x * v.x + v.y * v.y + v.z * v.z + v.w * v.w;
        }
        for (int m = 32; m; m >>= 1) ss += __shfl_xor(ss, m, 64);
        if ((t & 63) == 0) red[t >> 6] = ss;
        __syncthreads();
        float tot = red[0] + red[1] + red[2] + red[3];
        float r = rsqrtf(tot / (float)HIDD + RMS_EPS);
        uint2* xr = (uint2*)(xn + (size_t)row * HIDD);
        for (int i = t; i < HIDD / 4; i += 256) {
            float4 v = hr4[i], s4 = sc4[i];
            unsigned int lo = (unsigned)f2bf(v.x * r * s4.x) | ((unsigned)f2bf(v.y * r * s4.y) << 16);
            unsigned int hi = (unsigned)f2bf(v.z * r * s4.z) | ((unsigned)f2bf(v.w * r * s4.w) << 16);
            uint2 o; o.x = lo; o.y = hi;
            xr[i] = o;
        }
    } else {
        int idx = (blk - 2512) * 256 + t;     // < 32768 = T_SEQ*32
        int tt = idx >> 5, i = idx & 31;
        double freq = pow(150000.0, (double)(2 * i) / 64.0);
        double lnbase = log(150000.0);
        double low  = 32.0 * log(4096.0 / (32.0 * 2.0 * M_PI)) / lnbase;
        double high = 32.0 * log(4096.0 / (2.0 * M_PI)) / lnbase;
        double ramp = ((double)i - low) / (high - low);
        double mask = 1.0 - fmin(fmax(ramp, 0.0), 1.0);
        double invf = (1.0 / (32.0 * freq)) * (1.0 - mask) + (1.0 / freq) * mask;
        double conc = 0.1 * log(32.0) + 1.0;
        double ang = (double)positions[tt] * invf;
        // reduce mod 2pi in double; evaluate sincos in float (err << bf16 ulp)
        double tw = floor(ang * (1.0 / (2.0 * M_PI)));
        float ar = (float)(ang - tw * (2.0 * M_PI));
        tabc[idx] = cosf(ar) * (float)conc;
        tabs[idx] = sinf(ar) * (float)conc;
    }
}

// ---------------- 256x256 8-phase MFMA bf16 GEMM partial (split-K) -----------
// T2 (st swizzle, slot^row&7) + T3/T4 (8-phase counted vmcnt) + T5 (setprio).
// 8 waves (2M x 4N); per-wave output 128x64 split into 2x2 quadrants so each
// phase reads exactly one A-half and one B-half (half-tile-granular prefetch).
// LDS: 2 kt-slots x {A,B} x 2 halves x [128][64] bf16 = 128 KiB, 1 block/CU.
//
// Steady-state load calendar (per 8-phase iteration, kt a=2i slot0, b=2i+1 slot1):
//   ph1: stage B(b)h1, A(b)h1          (consumed ph6/ph7 this iter)
//   ph3: stage A(a+2)h0                (consumed next ph1)
//   ph4: stage B(a+2)h0; vmcnt(8)      (forces prev ph7/ph8 loads -> ph5 safe)
//   ph5: stage B(a+2)h1, A(a+2)h1; vmcnt(8)  (forces ph1 loads -> ph6/7 safe)
//   ph7: stage A(a+3)h0
//   ph8: stage B(a+3)h0; vmcnt(4)      (forces ph3..ph5 loads -> next ph1-3 safe)
// Every stage lands in a slot whose last reader was the previous phase
// (reads drained by that phase's lgkmcnt(0) + barrier) -> WAR-safe.

#define SYNCPRE() do { \
    __builtin_amdgcn_s_barrier(); \
    asm volatile("s_waitcnt lgkmcnt(0)"); \
    __builtin_amdgcn_s_setprio(1); \
} while (0)
#define SYNCPOST() do { \
    __builtin_amdgcn_s_setprio(0); \
    __builtin_amdgcn_s_barrier(); \
} while (0)

#define LDA_FRAGS(SLOT, QM) do { \
    const unsigned short* _pa = lds + ((SLOT)*4 + (QM)) * 8192 + rowA * 64; \
    _Pragma("unroll") \
    for (int _t = 0; _t < 4; ++_t) { \
        af[_t][0] = *(const short8*)(_pa + _t * 1024 + sl0); \
        af[_t][1] = *(const short8*)(_pa + _t * 1024 + sl1); \
    } \
} while (0)

#define LDB_FRAGS(SLOT, QN, BF) do { \
    const unsigned short* _pb = lds + ((SLOT)*4 + 2 + (QN)) * 8192 + rowB * 64; \
    _Pragma("unroll") \
    for (int _u = 0; _u < 2; ++_u) { \
        BF[_u][0] = *(const short8*)(_pb + _u * 1024 + sl0); \
        BF[_u][1] = *(const short8*)(_pb + _u * 1024 + sl1); \
    } \
} while (0)

#define MFMA_Q(QM, QN, BF) do { \
    _Pragma("unroll") \
    for (int _t = 0; _t < 4; ++_t) { \
        _Pragma("unroll") \
        for (int _u = 0; _u < 2; ++_u) { \
            floatx4 _c = acc[QM][_t][QN][_u]; \
            _c = __builtin_amdgcn_mfma_f32_16x16x32_bf16(af[_t][0], BF[_u][0], _c, 0, 0, 0); \
            _c = __builtin_amdgcn_mfma_f32_16x16x32_bf16(af[_t][1], BF[_u][1], _c, 0, 0, 0); \
            acc[QM][_t][QN][_u] = _c; \
        } \
    } \
} while (0)

// stage one half-tile (128 rows x 64 k) of mat into LDS: linear dest, global
// source pre-permuted by the inverse swizzle (rule 21: both-sides-or-neither).
#define STAGE(SLOT, MAT, HALF, GP, GR0, KT) do { \
    unsigned short* _d = lds + ((SLOT)*4 + (MAT)*2 + (HALF)) * 8192 + stdst; \
    const unsigned short* _s = (GP) + (size_t)((GR0) + (HALF)*128 + st_r0) * K + kbeg + (KT)*64 + st_c0; \
    glds16(_s, _d); \
    glds16(_s + (size_t)8 * K, _d + 512); \
} while (0)

template <int NX>
__global__ __launch_bounds__(512, 2) void gemm256_kernel(
    const unsigned short* __restrict__ A, const unsigned short* __restrict__ BT,
    unsigned short* __restrict__ P, int M, int N, int K, int Ks)
{
    __shared__ unsigned short lds[65536];   // 128 KiB

    // bijective XCD swizzle (grid % 8 == 0), y fastest -> XCD shares A/B panels
    int b = blockIdx.x;
    int cpx = (int)gridDim.x >> 3;
    int sid = (b & 7) * cpx + (b >> 3);
    int y = sid & 3;
    int xz = sid >> 2;
    int x = xz % NX, z = xz / NX;
    int m0 = y * 256, n0 = x * 256;
    int kbeg = z * Ks;
    int kslice = K - kbeg; if (kslice > Ks) kslice = Ks;   // uneven split-K ok
    int NT = kslice >> 6;    // K-tiles of 64
    int NIT = NT >> 1;

    int tid = threadIdx.x;
    int ln = tid & 63, wv = tid >> 6;
    int l16 = ln & 15, quad = ln >> 4;
    int wm = wv >> 2, wn = wv & 3;
    int e8 = l16 & 7;
    int sl0 = ((quad ^ e8) << 3);          // swizzled slot for kk=0 (shorts)
    int sl1 = (((4 + quad) ^ e8) << 3);    // swizzled slot for kk=1
    int rowA = wm * 64 + l16;              // A frag base row within half
    int rowB = wn * 32 + l16;              // B frag base row within half
    int st_r0 = (wv << 4) + (ln >> 3);     // staging row within half
    int st_c0 = (((ln & 7) ^ ((ln >> 3) & 7)) << 3);  // inverse-swizzled src col
    int stdst = (wv << 10) + (ln << 3);    // staging LDS dest (shorts)

    short8 af[4][2], b0[2][2], b1[2][2];
    floatx4 acc[2][4][2][2];
#pragma unroll
    for (int qm = 0; qm < 2; ++qm)
#pragma unroll
        for (int t = 0; t < 4; ++t)
#pragma unroll
            for (int qn = 0; qn < 2; ++qn)
#pragma unroll
                for (int u = 0; u < 2; ++u)
                    acc[qm][t][qn][u] = (floatx4){0.f, 0.f, 0.f, 0.f};

    // prologue: slot0 = kt0 (all 4 halves), slot1 = kt1 h0 halves only
    // (kt1's h1 halves are staged at ph1 of iteration 0, as in steady state)
    STAGE(0, 0, 0, A,  m0, 0); STAGE(0, 0, 1, A,  m0, 0);
    STAGE(0, 1, 0, BT, n0, 0); STAGE(0, 1, 1, BT, n0, 0);
    STAGE(1, 0, 0, A,  m0, 1); STAGE(1, 1, 0, BT, n0, 1);
    asm volatile("s_waitcnt vmcnt(0)");
    __builtin_amdgcn_s_barrier();

    int a = 0;
    for (int i = 0; i < NIT; ++i, a += 2) {
        bool k2 = (a + 2) < NT, k3 = (a + 3) < NT;
        // ---- kt a (slot 0) ----
        // ph1: quad (0,0)
        LDA_FRAGS(0, 0); LDB_FRAGS(0, 0, b0);
        STAGE(1, 1, 1, BT, n0, a + 1); STAGE(1, 0, 1, A, m0, a + 1);
        SYNCPRE(); MFMA_Q(0, 0, b0); SYNCPOST();
        // ph2: quad (0,1)
        LDB_FRAGS(0, 1, b1);
        SYNCPRE(); MFMA_Q(0, 1, b1); SYNCPOST();
        // ph3: quad (1,0)
        LDA_FRAGS(0, 1);
        if (k2) STAGE(0, 0, 0, A, m0, a + 2);
        SYNCPRE(); MFMA_Q(1, 0, b0); SYNCPOST();
        // ph4: quad (1,1)
        if (k2) { STAGE(0, 1, 0, BT, n0, a + 2); asm volatile("s_waitcnt vmcnt(8)"); }
        else    { asm volatile("s_waitcnt vmcnt(4)"); }
        SYNCPRE(); MFMA_Q(1, 1, b1); SYNCPOST();
        // ---- kt a+1 (slot 1) ----
        // ph5: quad (0,0)
        LDA_FRAGS(1, 0); LDB_FRAGS(1, 0, b0);
        if (k2) { STAGE(0, 1, 1, BT, n0, a + 2); STAGE(0, 0, 1, A, m0, a + 2);
                  asm volatile("s_waitcnt vmcnt(8)"); }
        else    { asm volatile("s_waitcnt vmcnt(0)"); }
        SYNCPRE(); MFMA_Q(0, 0, b0); SYNCPOST();
        // ph6: quad (0,1)
        LDB_FRAGS(1, 1, b1);
        SYNCPRE(); MFMA_Q(0, 1, b1); SYNCPOST();
        // ph7: quad (1,0)
        LDA_FRAGS(1, 1);
        if (k3) STAGE(1, 0, 0, A, m0, a + 3);
        SYNCPRE(); MFMA_Q(1, 0, b0); SYNCPOST();
        // ph8: quad (1,1)
        if (k3) { STAGE(1, 1, 0, BT, n0, a + 3); asm volatile("s_waitcnt vmcnt(4)"); }
        else    { asm volatile("s_waitcnt vmcnt(0)"); }
        SYNCPRE(); MFMA_Q(1, 1, b1); SYNCPOST();
    }
    if (NT & 1) {   // tail K-tile (even index -> slot 0), no staging, drained
        LDA_FRAGS(0, 0); LDB_FRAGS(0, 0, b0);
        SYNCPRE(); MFMA_Q(0, 0, b0); SYNCPOST();
        LDB_FRAGS(0, 1, b1);
        SYNCPRE(); MFMA_Q(0, 1, b1); SYNCPOST();
        LDA_FRAGS(0, 1);
        SYNCPRE(); MFMA_Q(1, 0, b0); SYNCPOST();
        SYNCPRE(); MFMA_Q(1, 1, b1); SYNCPOST();
    }

    unsigned short* Pz = P + (size_t)z * M * N;
#pragma unroll
    for (int qm = 0; qm < 2; ++qm)
#pragma unroll
        for (int t = 0; t < 4; ++t) {
            int rbase = m0 + qm * 128 + wm * 64 + t * 16 + quad * 4;
#pragma unroll
            for (int qn = 0; qn < 2; ++qn)
#pragma unroll
                for (int u = 0; u < 2; ++u) {
                    int col = n0 + qn * 128 + wn * 32 + u * 16 + l16;
                    if (col < N) {
#pragma unroll
                        for (int r = 0; r < 4; ++r)
                            Pz[(size_t)(rbase + r) * N + col] = f2bf(acc[qm][t][qn][u][r]);
                    }
                }
        }
}

// ---------------- reduce: out = sum_z P2 + bias + resid (fp32) ---------------
__global__ __launch_bounds__(256) void reduce_out_kernel(
    const unsigned short* __restrict__ P, const float* __restrict__ bias,
    const float* __restrict__ resid, float* __restrict__ out)
{
    int idx = (blockIdx.x * 256 + threadIdx.x) * 4;   // over 1024*2880
    int n = idx % HIDD;
    float4 rv = *(const float4*)(resid + idx);
    float4 bv = *(const float4*)(bias + n);
    float a0 = bv.x + rv.x, a1 = bv.y + rv.y, a2 = bv.z + rv.z, a3 = bv.w + rv.w;
#pragma unroll
    for (int z = 0; z < Z2; ++z) {
        s16x4 p = *(const s16x4*)(P + (size_t)z * P2SZ + idx);
        a0 += bf2f((unsigned short)p[0]);
        a1 += bf2f((unsigned short)p[1]);
        a2 += bf2f((unsigned short)p[2]);
        a3 += bf2f((unsigned short)p[3]);
    }
    float4 ov = {a0, a1, a2, a3};
    *(float4*)(out + idx) = ov;
}

// ---------------- MFMA attention: fused qkv-reduce + rope + sinks ------------
__global__ __launch_bounds__(512) void attn_kernel(
    const unsigned short* __restrict__ P1, const float* __restrict__ b_qkv,
    const float* __restrict__ sinks,
    const float* __restrict__ tabc, const float* __restrict__ tabs,
    unsigned short* __restrict__ attn)
{
    int i0 = blockIdx.x * 16;
    int kh = blockIdx.y;
    int tid = threadIdx.x, lane = tid & 63, g = tid >> 6;
    int quad = lane >> 4, l16 = lane & 15;
    int tile_j0 = i0 - 127;

    __shared__ unsigned short sU[8 * 16 * 168];   // 43008 B: sK then sP overlay
    __shared__ unsigned short sVt[64 * 168];      // 21504 B
    unsigned short* sK = sU;                      // [144][72] during QK phase
    unsigned short* sPw = sU + g * 16 * 168;      // per-wave P after QK phase

    {
        int d = lane, dd = lane & 31;
        float kb1 = b_qkv[KOFF + kh * 64 + d];
        float kb2 = b_qkv[KOFF + kh * 64 + (d ^ 32)];
        float vb  = b_qkv[VOFF + kh * 64 + d];
        for (int it = 0; it < 18; ++it) {
            int s = it * 8 + g;               // 0..143
            int j = tile_j0 + s;
            unsigned short kst = 0, vst = 0;
            if (j >= 0 && j < T_SEQ) {
                size_t ko = (size_t)j * QKV_N + KOFF + kh * 64;
                float x1 = kb1, x2 = kb2, vv = vb;
#pragma unroll
                for (int z = 0; z < Z1; ++z) {
                    const unsigned short* Pz = P1 + (size_t)z * P1SZ;
                    x1 += bf2f(Pz[ko + d]);
                    x2 += bf2f(Pz[ko + (d ^ 32)]);
                    vv += bf2f(Pz[ko + 512 + d]);
                }
                float c = tabc[j * 32 + dd], sn = tabs[j * 32 + dd];
                kst = f2bf((d < 32) ? (x1 * c - x2 * sn) : (x1 * c + x2 * sn));
                vst = f2bf(vv);
            }
            sK[s * 72 + d] = kst;
            sVt[d * 168 + s] = vst;
        }
        sVt[d * 168 + 144 + 2 * g]     = 0;
        sVt[d * 168 + 144 + 2 * g + 1] = 0;
    }

    int qi = i0 + l16;
    int hb = (kh * GQ + g) * 64;
    short8 qa, qb;
    {
        size_t qo = (size_t)qi * QKV_N + hb + quad * 8;
        float x1[8], x2[8];
#pragma unroll
        for (int j = 0; j < 8; ++j) {
            x1[j] = b_qkv[hb + quad * 8 + j];
            x2[j] = b_qkv[hb + quad * 8 + 32 + j];
        }
#pragma unroll
        for (int z = 0; z < Z1; ++z) {
            const unsigned short* Pz = P1 + (size_t)z * P1SZ;
            short8 lo = *(const short8*)(Pz + qo);
            short8 hi = *(const short8*)(Pz + qo + 32);
#pragma unroll
            for (int j = 0; j < 8; ++j) {
                x1[j] += bf2f((unsigned short)lo[j]);
                x2[j] += bf2f((unsigned short)hi[j]);
            }
        }
        const float* cc = tabc + qi * 32 + quad * 8;
        const float* sc = tabs + qi * 32 + quad * 8;
#pragma unroll
        for (int j = 0; j < 8; ++j) {
            float c = cc[j] * 0.125f, sn = sc[j] * 0.125f;
            qa[j] = (short)f2bf(x1[j] * c - x2[j] * sn);
            qb[j] = (short)f2bf(x2[j] * c + x1[j] * sn);
        }
    }
    __syncthreads();

    floatx4 Sc[9];
#pragma unroll
    for (int nt = 0; nt < 9; ++nt) Sc[nt] = (floatx4){0.f, 0.f, 0.f, 0.f};
#pragma unroll
    for (int nt = 0; nt < 9; ++nt) {
        short8 kb0 = *(const short8*)&sK[(nt * 16 + l16) * 72 + quad * 8];
        short8 kb1 = *(const short8*)&sK[(nt * 16 + l16) * 72 + 32 + quad * 8];
        Sc[nt] = __builtin_amdgcn_mfma_f32_16x16x32_bf16(qa, kb0, Sc[nt], 0, 0, 0);
        Sc[nt] = __builtin_amdgcn_mfma_f32_16x16x32_bf16(qb, kb1, Sc[nt], 0, 0, 0);
    }

    int smin = 127 - i0;
    float mx[4], sm[4], inv[4];
#pragma unroll
    for (int r = 0; r < 4; ++r) {
        int qoff = quad * 4 + r;
        int lo = qoff > smin ? qoff : smin;
        int hi = qoff + 127;
        float m = -INFINITY;
#pragma unroll
        for (int nt = 0; nt < 9; ++nt) {
            int s = nt * 16 + l16;
            float v = (s >= lo && s <= hi) ? Sc[nt][r] : -INFINITY;
            Sc[nt][r] = v;
            m = fmaxf(m, v);
        }
        mx[r] = m;
    }
#pragma unroll
    for (int mmask = 1; mmask < 16; mmask <<= 1)
#pragma unroll
        for (int r = 0; r < 4; ++r)
            mx[r] = fmaxf(mx[r], __shfl_xor(mx[r], mmask, 64));
    float sink = sinks[kh * GQ + g];
#pragma unroll
    for (int r = 0; r < 4; ++r) {
        mx[r] = fmaxf(mx[r], sink);
        float s = 0.f;
#pragma unroll
        for (int nt = 0; nt < 9; ++nt) {
            float p = __expf(Sc[nt][r] - mx[r]);
            Sc[nt][r] = p;
            s += p;
        }
        sm[r] = s;
    }
#pragma unroll
    for (int mmask = 1; mmask < 16; mmask <<= 1)
#pragma unroll
        for (int r = 0; r < 4; ++r)
            sm[r] += __shfl_xor(sm[r], mmask, 64);
#pragma unroll
    for (int r = 0; r < 4; ++r)
        inv[r] = 1.f / (sm[r] + __expf(sink - mx[r]));

    __syncthreads();   // all waves done reading sK before sP overlays it

#pragma unroll
    for (int nt = 0; nt < 9; ++nt)
#pragma unroll
        for (int r = 0; r < 4; ++r)
            sPw[(quad * 4 + r) * 168 + nt * 16 + l16] = f2bf(Sc[nt][r]);
    {
        int q = lane >> 2, so = (lane & 3) * 4;
        *(s16x4*)&sPw[q * 168 + 144 + so] = (s16x4){0, 0, 0, 0};
    }

    floatx4 O[4];
#pragma unroll
    for (int nt = 0; nt < 4; ++nt) O[nt] = (floatx4){0.f, 0.f, 0.f, 0.f};
#pragma unroll
    for (int kt = 0; kt < 5; ++kt) {
        short8 pa = *(const short8*)&sPw[l16 * 168 + kt * 32 + quad * 8];
#pragma unroll
        for (int nt = 0; nt < 4; ++nt) {
            short8 vb = *(const short8*)&sVt[(nt * 16 + l16) * 168 + kt * 32 + quad * 8];
            O[nt] = __builtin_amdgcn_mfma_f32_16x16x32_bf16(pa, vb, O[nt], 0, 0, 0);
        }
    }
#pragma unroll
    for (int nt = 0; nt < 4; ++nt)
#pragma unroll
        for (int r = 0; r < 4; ++r) {
            int q = quad * 4 + r;
            attn[(size_t)(i0 + q) * QDIM + (kh * GQ + g) * 64 + nt * 16 + l16] =
                f2bf(O[nt][r] * inv[r]);
        }
}

// ---------------- launch -----------------------------------------------------
extern "C" void kernel_launch(void* const* d_in, const int* in_sizes, int n_in,
                              void* d_out, int out_size, void* d_ws, size_t ws_size,
                              hipStream_t stream)
{
    const float* hidden     = (const float*)d_in[0];
    const int*   positions  = (const int*)d_in[1];
    const float* norm_scale = (const float*)d_in[2];
    const float* w_qkv      = (const float*)d_in[3];
    const float* b_qkv      = (const float*)d_in[4];
    const float* w_out      = (const float*)d_in[5];
    const float* b_out      = (const float*)d_in[6];
    const float* sinks      = (const float*)d_in[7];
    float* out = (float*)d_out;

    char* ws = (char*)d_ws;
    float*          tabc  = (float*)ws;                        //     131,072
    float*          tabs  = (float*)(ws + 131072);             //     131,072
    unsigned short* boutT = (unsigned short*)(ws + 262144);    //  25,165,824 (3072x4096)
    unsigned short* xn    = (unsigned short*)(ws + 25427968);  //   5,898,240
    unsigned short* bqkvT = (unsigned short*)(ws + 31326208);  //  29,491,200
    unsigned short* P1    = (unsigned short*)(ws + 60817408);  //  31,457,280 (Z1 slices)
    unsigned short* attnb = (unsigned short*)(ws + 25427968);  //   8,388,608 (aliases
                                                               //   xn+bqkvT, both dead
                                                               //   before attn writes)
    unsigned short* P2    = (unsigned short*)(ws + 60817408);  //  29,491,200 (Z2=5 slices;
                                                               //   aliases P1, dead
                                                               //   before GEMM2 runs)
    // high-water: 92,274,688 B

    prep_kernel<<<2640, 256, 0, stream>>>(
        w_qkv, w_out, hidden, norm_scale, positions, bqkvT, boutT, xn, tabc, tabs);
    gemm256_kernel<20><<<4 * 20 * Z1, 512, 0, stream>>>(
        xn, bqkvT, P1, T_SEQ, QKV_N, HIDD, KS1);
    attn_kernel<<<dim3(T_SEQ / 16, NKVH), 512, 0, stream>>>(
        P1, b_qkv, sinks, tabc, tabs, attnb);
    gemm256_kernel<12><<<4 * 12 * Z2, 512, 0, stream>>>(
        attnb, boutT, P2, T_SEQ, HIDD, QDIM, KS2);
    reduce_out_kernel<<<2880, 256, 0, stream>>>(P2, b_out, hidden, out);
}

// Round 3
// 249.408 us; speedup vs baseline: 1.0593x; 1.0593x over previous
//
#include <hip/hip_runtime.h>
#include <hip/hip_bf16.h>
#include <math.h>

#define T_SEQ 1024
#define HIDD 2880
#define NH   64
#define NKVH 8
#define GQ   8
#define HD   64
#define WIN  128
#define QKV_N 5120     // NH*HD + 2*NKVH*HD
#define QDIM  4096     // NH*HD
#define KOFF  4096
#define VOFF  4608
#define NPAD_OUT 3072  // HIDD padded to 12*256 tiles (256-wide N tiling)
#define RMS_EPS 1e-5f
#define Z1 3
#define KS1 960
#define Z2 5
#define KS2 832        // 4 slices of 832 + 1 slice of 768
#define P1SZ (T_SEQ * QKV_N)   // elems per GEMM1 partial slice
#define P2SZ (T_SEQ * HIDD)    // elems per GEMM2 partial slice

typedef __attribute__((ext_vector_type(8))) short short8;
typedef __attribute__((ext_vector_type(4))) short s16x4;
typedef __attribute__((ext_vector_type(4))) float floatx4;

__device__ __forceinline__ float bf2f(unsigned short u) {
    unsigned int x = ((unsigned int)u) << 16;
    float f; __builtin_memcpy(&f, &x, 4); return f;
}
__device__ __forceinline__ unsigned short f2bf(float f) {
    unsigned int x; __builtin_memcpy(&x, &f, 4);
    unsigned int r = (x + 0x7fffu + ((x >> 16) & 1u)) >> 16;
    return (unsigned short)r;
}
__device__ __forceinline__ void glds16(const unsigned short* g, unsigned short* l) {
    __builtin_amdgcn_global_load_lds(
        (const __attribute__((address_space(1))) void*)g,
        (__attribute__((address_space(3))) void*)l, 16, 0, 0);
}

// ---------------- prep: transposes + rmsnorm + rope table (fused) ------------
// 64x66 LDS tiles (8.7 KB) -> ~67% occupancy; proven 54 us config (round 1).
__global__ __launch_bounds__(256) void prep_kernel(
    const float* __restrict__ w_qkv, const float* __restrict__ w_out,
    const float* __restrict__ hidden, const float* __restrict__ norm_scale,
    const int* __restrict__ positions,
    unsigned short* __restrict__ bqkvT, unsigned short* __restrict__ boutT,
    unsigned short* __restrict__ xn,
    float* __restrict__ tabc, float* __restrict__ tabs)
{
    __shared__ unsigned short tile[64 * 66];   // stride 66: <=2-way conflicts
    __shared__ float red[4];
    int blk = blockIdx.x;
    int t = threadIdx.x;

    if (blk < 6672) {
        const float* in; unsigned short* out; int R, C, bx, by;
        if (blk < 3600) { in = w_qkv; out = bqkvT; R = HIDD; C = QKV_N; bx = blk % 80; by = blk / 80; }
        else { int r = blk - 3600; in = w_out; out = boutT; R = QDIM; C = HIDD; bx = r % 48; by = r / 48; }
        int r0 = by * 64, c0 = bx * 64;
        bool inr = (c0 < C);   // uniform per tile (C multiple of 64)
#pragma unroll
        for (int p = 0; p < 4; ++p) {
            int row = p * 16 + (t >> 4);
            int col = (t & 15) * 4;
            float4 v = inr ? *(const float4*)&in[(size_t)(r0 + row) * C + c0 + col]
                           : make_float4(0.f, 0.f, 0.f, 0.f);
            unsigned int w0 = (unsigned)f2bf(v.x) | ((unsigned)f2bf(v.y) << 16);
            unsigned int w1 = (unsigned)f2bf(v.z) | ((unsigned)f2bf(v.w) << 16);
            *(unsigned int*)&tile[row * 66 + col]     = w0;
            *(unsigned int*)&tile[row * 66 + col + 2] = w1;
        }
        __syncthreads();
        int oc = t >> 2, ks = (t & 3) * 16;
        unsigned short vbuf[16];
#pragma unroll
        for (int j = 0; j < 16; ++j) vbuf[j] = tile[(ks + j) * 66 + oc];
        unsigned short* dst = &out[(size_t)(c0 + oc) * R + r0 + ks];
        *(uint4*)dst       = *(uint4*)&vbuf[0];
        *(uint4*)(dst + 8) = *(uint4*)&vbuf[8];
    } else if (blk < 7696) {
        int row = blk - 6672;
        const float4* hr4 = (const float4*)(hidden + (size_t)row * HIDD);
        const float4* sc4 = (const float4*)norm_scale;
        float ss = 0.f;
        for (int i = t; i < HIDD / 4; i += 256) {
            float4 v = hr4[i];
            ss += v.x * v.x + v.y * v.y + v.z * v.z + v.w * v.w;
        }
        for (int m = 32; m; m >>= 1) ss += __shfl_xor(ss, m, 64);
        if ((t & 63) == 0) red[t >> 6] = ss;
        __syncthreads();
        float tot = red[0] + red[1] + red[2] + red[3];
        float r = rsqrtf(tot / (float)HIDD + RMS_EPS);
        uint2* xr = (uint2*)(xn + (size_t)row * HIDD);
        for (int i = t; i < HIDD / 4; i += 256) {
            float4 v = hr4[i], s4 = sc4[i];
            unsigned int lo = (unsigned)f2bf(v.x * r * s4.x) | ((unsigned)f2bf(v.y * r * s4.y) << 16);
            unsigned int hi = (unsigned)f2bf(v.z * r * s4.z) | ((unsigned)f2bf(v.w * r * s4.w) << 16);
            uint2 o; o.x = lo; o.y = hi;
            xr[i] = o;
        }
    } else {
        int idx = (blk - 7696) * 256 + t;     // < 32768 = T_SEQ*32
        int tt = idx >> 5, i = idx & 31;
        double freq = pow(150000.0, (double)(2 * i) / 64.0);
        double lnbase = log(150000.0);
        double low  = 32.0 * log(4096.0 / (32.0 * 2.0 * M_PI)) / lnbase;
        double high = 32.0 * log(4096.0 / (2.0 * M_PI)) / lnbase;
        double ramp = ((double)i - low) / (high - low);
        double mask = 1.0 - fmin(fmax(ramp, 0.0), 1.0);
        double invf = (1.0 / (32.0 * freq)) * (1.0 - mask) + (1.0 / freq) * mask;
        double conc = 0.1 * log(32.0) + 1.0;
        double ang = (double)positions[tt] * invf;
        // reduce mod 2pi in double; evaluate sincos in float (err << bf16 ulp)
        double tw = floor(ang * (1.0 / (2.0 * M_PI)));
        float ar = (float)(ang - tw * (2.0 * M_PI));
        tabc[idx] = cosf(ar) * (float)conc;
        tabs[idx] = sinf(ar) * (float)conc;
    }
}

// ---------------- 256x256 8-phase MFMA bf16 GEMM partial (split-K) -----------
// T2 (st swizzle, slot^row&7) + T3/T4 (8-phase counted vmcnt) + T5 (setprio).
// 8 waves (2M x 4N); per-wave output 128x64 split into 2x2 quadrants so each
// phase reads exactly one A-half and one B-half (half-tile-granular prefetch).
// LDS: 2 kt-slots x {A,B} x 2 halves x [128][64] bf16 = 128 KiB, 1 block/CU.
//
// Steady-state load calendar (per 8-phase iteration, kt a=2i slot0, b=2i+1 slot1):
//   ph1: stage B(b)h1, A(b)h1          (consumed ph6/ph7 this iter)
//   ph3: stage A(a+2)h0                (consumed next ph1)
//   ph4: stage B(a+2)h0; vmcnt(8)      (forces prev ph7/ph8 loads -> ph5 safe)
//   ph5: stage B(a+2)h1, A(a+2)h1; vmcnt(8)  (forces ph1 loads -> ph6/7 safe)
//   ph7: stage A(a+3)h0
//   ph8: stage B(a+3)h0; vmcnt(4)      (forces ph3..ph5 loads -> next ph1-3 safe)
// Every stage lands in a slot whose last reader was the previous phase
// (reads drained by that phase's lgkmcnt(0) + barrier) -> WAR-safe.

#define SYNCPRE() do { \
    __builtin_amdgcn_s_barrier(); \
    asm volatile("s_waitcnt lgkmcnt(0)"); \
    __builtin_amdgcn_s_setprio(1); \
} while (0)
#define SYNCPOST() do { \
    __builtin_amdgcn_s_setprio(0); \
    __builtin_amdgcn_s_barrier(); \
} while (0)

#define LDA_FRAGS(SLOT, QM) do { \
    const unsigned short* _pa = lds + ((SLOT)*4 + (QM)) * 8192 + rowA * 64; \
    _Pragma("unroll") \
    for (int _t = 0; _t < 4; ++_t) { \
        af[_t][0] = *(const short8*)(_pa + _t * 1024 + sl0); \
        af[_t][1] = *(const short8*)(_pa + _t * 1024 + sl1); \
    } \
} while (0)

#define LDB_FRAGS(SLOT, QN, BF) do { \
    const unsigned short* _pb = lds + ((SLOT)*4 + 2 + (QN)) * 8192 + rowB * 64; \
    _Pragma("unroll") \
    for (int _u = 0; _u < 2; ++_u) { \
        BF[_u][0] = *(const short8*)(_pb + _u * 1024 + sl0); \
        BF[_u][1] = *(const short8*)(_pb + _u * 1024 + sl1); \
    } \
} while (0)

#define MFMA_Q(QM, QN, BF) do { \
    _Pragma("unroll") \
    for (int _t = 0; _t < 4; ++_t) { \
        _Pragma("unroll") \
        for (int _u = 0; _u < 2; ++_u) { \
            floatx4 _c = acc[QM][_t][QN][_u]; \
            _c = __builtin_amdgcn_mfma_f32_16x16x32_bf16(af[_t][0], BF[_u][0], _c, 0, 0, 0); \
            _c = __builtin_amdgcn_mfma_f32_16x16x32_bf16(af[_t][1], BF[_u][1], _c, 0, 0, 0); \
            acc[QM][_t][QN][_u] = _c; \
        } \
    } \
} while (0)

// stage one half-tile (128 rows x 64 k) of mat into LDS: linear dest, global
// source pre-permuted by the inverse swizzle (rule 21: both-sides-or-neither).
#define STAGE(SLOT, MAT, HALF, GP, GR0, KT) do { \
    unsigned short* _d = lds + ((SLOT)*4 + (MAT)*2 + (HALF)) * 8192 + stdst; \
    const unsigned short* _s = (GP) + (size_t)((GR0) + (HALF)*128 + st_r0) * K + kbeg + (KT)*64 + st_c0; \
    glds16(_s, _d); \
    glds16(_s + (size_t)8 * K, _d + 512); \
} while (0)

template <int NX>
__global__ __launch_bounds__(512, 2) void gemm256_kernel(
    const unsigned short* __restrict__ A, const unsigned short* __restrict__ BT,
    unsigned short* __restrict__ P, int M, int N, int K, int Ks)
{
    __shared__ unsigned short lds[65536];   // 128 KiB

    // bijective XCD swizzle (grid % 8 == 0), y fastest -> XCD shares A/B panels
    int b = blockIdx.x;
    int cpx = (int)gridDim.x >> 3;
    int sid = (b & 7) * cpx + (b >> 3);
    int y = sid & 3;
    int xz = sid >> 2;
    int x = xz % NX, z = xz / NX;
    int m0 = y * 256, n0 = x * 256;
    int kbeg = z * Ks;
    int kslice = K - kbeg; if (kslice > Ks) kslice = Ks;   // uneven split-K ok
    int NT = kslice >> 6;    // K-tiles of 64
    int NIT = NT >> 1;

    int tid = threadIdx.x;
    int ln = tid & 63, wv = tid >> 6;
    int l16 = ln & 15, quad = ln >> 4;
    int wm = wv >> 2, wn = wv & 3;
    int e8 = l16 & 7;
    int sl0 = ((quad ^ e8) << 3);          // swizzled slot for kk=0 (shorts)
    int sl1 = (((4 + quad) ^ e8) << 3);    // swizzled slot for kk=1
    int rowA = wm * 64 + l16;              // A frag base row within half
    int rowB = wn * 32 + l16;              // B frag base row within half
    int st_r0 = (wv << 4) + (ln >> 3);     // staging row within half
    int st_c0 = (((ln & 7) ^ ((ln >> 3) & 7)) << 3);  // inverse-swizzled src col
    int stdst = (wv << 10) + (ln << 3);    // staging LDS dest (shorts)

    short8 af[4][2], b0[2][2], b1[2][2];
    floatx4 acc[2][4][2][2];
#pragma unroll
    for (int qm = 0; qm < 2; ++qm)
#pragma unroll
        for (int t = 0; t < 4; ++t)
#pragma unroll
            for (int qn = 0; qn < 2; ++qn)
#pragma unroll
                for (int u = 0; u < 2; ++u)
                    acc[qm][t][qn][u] = (floatx4){0.f, 0.f, 0.f, 0.f};

    // prologue: slot0 = kt0 (all 4 halves), slot1 = kt1 h0 halves only
    // (kt1's h1 halves are staged at ph1 of iteration 0, as in steady state)
    STAGE(0, 0, 0, A,  m0, 0); STAGE(0, 0, 1, A,  m0, 0);
    STAGE(0, 1, 0, BT, n0, 0); STAGE(0, 1, 1, BT, n0, 0);
    STAGE(1, 0, 0, A,  m0, 1); STAGE(1, 1, 0, BT, n0, 1);
    asm volatile("s_waitcnt vmcnt(0)");
    __builtin_amdgcn_s_barrier();

    int a = 0;
    for (int i = 0; i < NIT; ++i, a += 2) {
        bool k2 = (a + 2) < NT, k3 = (a + 3) < NT;
        // ---- kt a (slot 0) ----
        // ph1: quad (0,0)
        LDA_FRAGS(0, 0); LDB_FRAGS(0, 0, b0);
        STAGE(1, 1, 1, BT, n0, a + 1); STAGE(1, 0, 1, A, m0, a + 1);
        SYNCPRE(); MFMA_Q(0, 0, b0); SYNCPOST();
        // ph2: quad (0,1)
        LDB_FRAGS(0, 1, b1);
        SYNCPRE(); MFMA_Q(0, 1, b1); SYNCPOST();
        // ph3: quad (1,0)
        LDA_FRAGS(0, 1);
        if (k2) STAGE(0, 0, 0, A, m0, a + 2);
        SYNCPRE(); MFMA_Q(1, 0, b0); SYNCPOST();
        // ph4: quad (1,1)
        if (k2) { STAGE(0, 1, 0, BT, n0, a + 2); asm volatile("s_waitcnt vmcnt(8)"); }
        else    { asm volatile("s_waitcnt vmcnt(4)"); }
        SYNCPRE(); MFMA_Q(1, 1, b1); SYNCPOST();
        // ---- kt a+1 (slot 1) ----
        // ph5: quad (0,0)
        LDA_FRAGS(1, 0); LDB_FRAGS(1, 0, b0);
        if (k2) { STAGE(0, 1, 1, BT, n0, a + 2); STAGE(0, 0, 1, A, m0, a + 2);
                  asm volatile("s_waitcnt vmcnt(8)"); }
        else    { asm volatile("s_waitcnt vmcnt(0)"); }
        SYNCPRE(); MFMA_Q(0, 0, b0); SYNCPOST();
        // ph6: quad (0,1)
        LDB_FRAGS(1, 1, b1);
        SYNCPRE(); MFMA_Q(0, 1, b1); SYNCPOST();
        // ph7: quad (1,0)
        LDA_FRAGS(1, 1);
        if (k3) STAGE(1, 0, 0, A, m0, a + 3);
        SYNCPRE(); MFMA_Q(1, 0, b0); SYNCPOST();
        // ph8: quad (1,1)
        if (k3) { STAGE(1, 1, 0, BT, n0, a + 3); asm volatile("s_waitcnt vmcnt(4)"); }
        else    { asm volatile("s_waitcnt vmcnt(0)"); }
        SYNCPRE(); MFMA_Q(1, 1, b1); SYNCPOST();
    }
    if (NT & 1) {   // tail K-tile (even index -> slot 0), no staging, drained
        LDA_FRAGS(0, 0); LDB_FRAGS(0, 0, b0);
        SYNCPRE(); MFMA_Q(0, 0, b0); SYNCPOST();
        LDB_FRAGS(0, 1, b1);
        SYNCPRE(); MFMA_Q(0, 1, b1); SYNCPOST();
        LDA_FRAGS(0, 1);
        SYNCPRE(); MFMA_Q(1, 0, b0); SYNCPOST();
        SYNCPRE(); MFMA_Q(1, 1, b1); SYNCPOST();
    }

    unsigned short* Pz = P + (size_t)z * M * N;
#pragma unroll
    for (int qm = 0; qm < 2; ++qm)
#pragma unroll
        for (int t = 0; t < 4; ++t) {
            int rbase = m0 + qm * 128 + wm * 64 + t * 16 + quad * 4;
#pragma unroll
            for (int qn = 0; qn < 2; ++qn)
#pragma unroll
                for (int u = 0; u < 2; ++u) {
                    int col = n0 + qn * 128 + wn * 32 + u * 16 + l16;
                    if (col < N) {
#pragma unroll
                        for (int r = 0; r < 4; ++r)
                            Pz[(size_t)(rbase + r) * N + col] = f2bf(acc[qm][t][qn][u][r]);
                    }
                }
        }
}

// ---------------- reduce: out = sum_z P2 + bias + resid (fp32) ---------------
__global__ __launch_bounds__(256) void reduce_out_kernel(
    const unsigned short* __restrict__ P, const float* __restrict__ bias,
    const float* __restrict__ resid, float* __restrict__ out)
{
    int idx = (blockIdx.x * 256 + threadIdx.x) * 4;   // over 1024*2880
    int n = idx % HIDD;
    float4 rv = *(const float4*)(resid + idx);
    float4 bv = *(const float4*)(bias + n);
    float a0 = bv.x + rv.x, a1 = bv.y + rv.y, a2 = bv.z + rv.z, a3 = bv.w + rv.w;
#pragma unroll
    for (int z = 0; z < Z2; ++z) {
        s16x4 p = *(const s16x4*)(P + (size_t)z * P2SZ + idx);
        a0 += bf2f((unsigned short)p[0]);
        a1 += bf2f((unsigned short)p[1]);
        a2 += bf2f((unsigned short)p[2]);
        a3 += bf2f((unsigned short)p[3]);
    }
    float4 ov = {a0, a1, a2, a3};
    *(float4*)(out + idx) = ov;
}

// ---------------- MFMA attention: fused qkv-reduce + rope + sinks ------------
// K/V staging vectorized: 8 threads per kv-row; 4 do K (short8 loads, rope in
// register, uint4 LDS stores), 4 do V (short8 loads, scalar transposed stores).
__global__ __launch_bounds__(512) void attn_kernel(
    const unsigned short* __restrict__ P1, const float* __restrict__ b_qkv,
    const float* __restrict__ sinks,
    const float* __restrict__ tabc, const float* __restrict__ tabs,
    unsigned short* __restrict__ attn)
{
    int i0 = blockIdx.x * 16;
    int kh = blockIdx.y;
    int tid = threadIdx.x, lane = tid & 63, g = tid >> 6;
    int quad = lane >> 4, l16 = lane & 15;
    int tile_j0 = i0 - 127;

    __shared__ unsigned short sU[8 * 16 * 168];   // 43008 B: sK then sP overlay
    __shared__ unsigned short sVt[64 * 168];      // 21504 B
    unsigned short* sK = sU;                      // [144][72] during QK phase
    unsigned short* sPw = sU + g * 16 * 168;      // per-wave P after QK phase

    {
        int rs = tid >> 3;      // row slot 0..63
        int c  = tid & 7;       // role: 0..3 K-chunks, 4..7 V-chunks
        if (c < 4) {
            int d0 = c * 8;
            float kb1[8], kb2[8];
#pragma unroll
            for (int jj = 0; jj < 8; ++jj) {
                kb1[jj] = b_qkv[KOFF + kh * 64 + d0 + jj];
                kb2[jj] = b_qkv[KOFF + kh * 64 + d0 + 32 + jj];
            }
            for (int it = 0; it < 3; ++it) {
                int s = it * 64 + rs;
                if (s < 144) {
                    int j = tile_j0 + s;
                    unsigned short olo[8], ohi[8];
                    if (j >= 0 && j < T_SEQ) {
                        float x1[8], x2[8];
#pragma unroll
                        for (int jj = 0; jj < 8; ++jj) { x1[jj] = kb1[jj]; x2[jj] = kb2[jj]; }
                        size_t ko = (size_t)j * QKV_N + KOFF + kh * 64 + d0;
#pragma unroll
                        for (int z = 0; z < Z1; ++z) {
                            const unsigned short* Pz = P1 + (size_t)z * P1SZ;
                            short8 lo = *(const short8*)(Pz + ko);
                            short8 hi = *(const short8*)(Pz + ko + 32);
#pragma unroll
                            for (int jj = 0; jj < 8; ++jj) {
                                x1[jj] += bf2f((unsigned short)lo[jj]);
                                x2[jj] += bf2f((unsigned short)hi[jj]);
                            }
                        }
                        const float* cc = tabc + j * 32 + d0;
                        const float* sc = tabs + j * 32 + d0;
#pragma unroll
                        for (int jj = 0; jj < 8; ++jj) {
                            float cj = cc[jj], sj = sc[jj];
                            olo[jj] = f2bf(x1[jj] * cj - x2[jj] * sj);
                            ohi[jj] = f2bf(x2[jj] * cj + x1[jj] * sj);
                        }
                    } else {
#pragma unroll
                        for (int jj = 0; jj < 8; ++jj) { olo[jj] = 0; ohi[jj] = 0; }
                    }
                    *(uint4*)&sK[s * 72 + d0]      = *(uint4*)olo;
                    *(uint4*)&sK[s * 72 + 32 + d0] = *(uint4*)ohi;
                }
            }
        } else {
            int d0 = (c - 4) * 16;
            float vbi[16];
#pragma unroll
            for (int jj = 0; jj < 16; ++jj) vbi[jj] = b_qkv[VOFF + kh * 64 + d0 + jj];
            for (int it = 0; it < 3; ++it) {
                int s = it * 64 + rs;
                if (s < 144) {
                    int j = tile_j0 + s;
                    if (j >= 0 && j < T_SEQ) {
                        float vv[16];
#pragma unroll
                        for (int jj = 0; jj < 16; ++jj) vv[jj] = vbi[jj];
                        size_t ko = (size_t)j * QKV_N + VOFF + kh * 64 + d0;
#pragma unroll
                        for (int z = 0; z < Z1; ++z) {
                            const unsigned short* Pz = P1 + (size_t)z * P1SZ;
                            short8 lo = *(const short8*)(Pz + ko);
                            short8 hi = *(const short8*)(Pz + ko + 8);
#pragma unroll
                            for (int jj = 0; jj < 8; ++jj) {
                                vv[jj]     += bf2f((unsigned short)lo[jj]);
                                vv[8 + jj] += bf2f((unsigned short)hi[jj]);
                            }
                        }
#pragma unroll
                        for (int jj = 0; jj < 16; ++jj)
                            sVt[(d0 + jj) * 168 + s] = f2bf(vv[jj]);
                    } else {
#pragma unroll
                        for (int jj = 0; jj < 16; ++jj)
                            sVt[(d0 + jj) * 168 + s] = 0;
                    }
                }
            }
        }
        // zero-pad V columns 144..159 (one b32 per thread covers 64x16)
        int zd = tid >> 3, zc = 144 + (tid & 7) * 2;
        *(unsigned int*)&sVt[zd * 168 + zc] = 0;
    }

    int qi = i0 + l16;
    int hb = (kh * GQ + g) * 64;
    short8 qa, qb;
    {
        size_t qo = (size_t)qi * QKV_N + hb + quad * 8;
        float x1[8], x2[8];
#pragma unroll
        for (int j = 0; j < 8; ++j) {
            x1[j] = b_qkv[hb + quad * 8 + j];
            x2[j] = b_qkv[hb + quad * 8 + 32 + j];
        }
#pragma unroll
        for (int z = 0; z < Z1; ++z) {
            const unsigned short* Pz = P1 + (size_t)z * P1SZ;
            short8 lo = *(const short8*)(Pz + qo);
            short8 hi = *(const short8*)(Pz + qo + 32);
#pragma unroll
            for (int j = 0; j < 8; ++j) {
                x1[j] += bf2f((unsigned short)lo[j]);
                x2[j] += bf2f((unsigned short)hi[j]);
            }
        }
        const float* cc = tabc + qi * 32 + quad * 8;
        const float* sc = tabs + qi * 32 + quad * 8;
#pragma unroll
        for (int j = 0; j < 8; ++j) {
            float c = cc[j] * 0.125f, sn = sc[j] * 0.125f;
            qa[j] = (short)f2bf(x1[j] * c - x2[j] * sn);
            qb[j] = (short)f2bf(x2[j] * c + x1[j] * sn);
        }
    }
    __syncthreads();

    floatx4 Sc[9];
#pragma unroll
    for (int nt = 0; nt < 9; ++nt) Sc[nt] = (floatx4){0.f, 0.f, 0.f, 0.f};
#pragma unroll
    for (int nt = 0; nt < 9; ++nt) {
        short8 kb0 = *(const short8*)&sK[(nt * 16 + l16) * 72 + quad * 8];
        short8 kb1 = *(const short8*)&sK[(nt * 16 + l16) * 72 + 32 + quad * 8];
        Sc[nt] = __builtin_amdgcn_mfma_f32_16x16x32_bf16(qa, kb0, Sc[nt], 0, 0, 0);
        Sc[nt] = __builtin_amdgcn_mfma_f32_16x16x32_bf16(qb, kb1, Sc[nt], 0, 0, 0);
    }

    int smin = 127 - i0;
    float mx[4], sm[4], inv[4];
#pragma unroll
    for (int r = 0; r < 4; ++r) {
        int qoff = quad * 4 + r;
        int lo = qoff > smin ? qoff : smin;
        int hi = qoff + 127;
        float m = -INFINITY;
#pragma unroll
        for (int nt = 0; nt < 9; ++nt) {
            int s = nt * 16 + l16;
            float v = (s >= lo && s <= hi) ? Sc[nt][r] : -INFINITY;
            Sc[nt][r] = v;
            m = fmaxf(m, v);
        }
        mx[r] = m;
    }
#pragma unroll
    for (int mmask = 1; mmask < 16; mmask <<= 1)
#pragma unroll
        for (int r = 0; r < 4; ++r)
            mx[r] = fmaxf(mx[r], __shfl_xor(mx[r], mmask, 64));
    float sink = sinks[kh * GQ + g];
#pragma unroll
    for (int r = 0; r < 4; ++r) {
        mx[r] = fmaxf(mx[r], sink);
        float s = 0.f;
#pragma unroll
        for (int nt = 0; nt < 9; ++nt) {
            float p = __expf(Sc[nt][r] - mx[r]);
            Sc[nt][r] = p;
            s += p;
        }
        sm[r] = s;
    }
#pragma unroll
    for (int mmask = 1; mmask < 16; mmask <<= 1)
#pragma unroll
        for (int r = 0; r < 4; ++r)
            sm[r] += __shfl_xor(sm[r], mmask, 64);
#pragma unroll
    for (int r = 0; r < 4; ++r)
        inv[r] = 1.f / (sm[r] + __expf(sink - mx[r]));

    __syncthreads();   // all waves done reading sK before sP overlays it

#pragma unroll
    for (int nt = 0; nt < 9; ++nt)
#pragma unroll
        for (int r = 0; r < 4; ++r)
            sPw[(quad * 4 + r) * 168 + nt * 16 + l16] = f2bf(Sc[nt][r]);
    {
        int q = lane >> 2, so = (lane & 3) * 4;
        *(s16x4*)&sPw[q * 168 + 144 + so] = (s16x4){0, 0, 0, 0};
    }

    floatx4 O[4];
#pragma unroll
    for (int nt = 0; nt < 4; ++nt) O[nt] = (floatx4){0.f, 0.f, 0.f, 0.f};
#pragma unroll
    for (int kt = 0; kt < 5; ++kt) {
        short8 pa = *(const short8*)&sPw[l16 * 168 + kt * 32 + quad * 8];
#pragma unroll
        for (int nt = 0; nt < 4; ++nt) {
            short8 vb = *(const short8*)&sVt[(nt * 16 + l16) * 168 + kt * 32 + quad * 8];
            O[nt] = __builtin_amdgcn_mfma_f32_16x16x32_bf16(pa, vb, O[nt], 0, 0, 0);
        }
    }
#pragma unroll
    for (int nt = 0; nt < 4; ++nt)
#pragma unroll
        for (int r = 0; r < 4; ++r) {
            int q = quad * 4 + r;
            attn[(size_t)(i0 + q) * QDIM + (kh * GQ + g) * 64 + nt * 16 + l16] =
                f2bf(O[nt][r] * inv[r]);
        }
}

// ---------------- launch -----------------------------------------------------
extern "C" void kernel_launch(void* const* d_in, const int* in_sizes, int n_in,
                              void* d_out, int out_size, void* d_ws, size_t ws_size,
                              hipStream_t stream)
{
    const float* hidden     = (const float*)d_in[0];
    const int*   positions  = (const int*)d_in[1];
    const float* norm_scale = (const float*)d_in[2];
    const float* w_qkv      = (const float*)d_in[3];
    const float* b_qkv      = (const float*)d_in[4];
    const float* w_out      = (const float*)d_in[5];
    const float* b_out      = (const float*)d_in[6];
    const float* sinks      = (const float*)d_in[7];
    float* out = (float*)d_out;

    char* ws = (char*)d_ws;
    float*          tabc  = (float*)ws;                        //     131,072
    float*          tabs  = (float*)(ws + 131072);             //     131,072
    unsigned short* boutT = (unsigned short*)(ws + 262144);    //  25,165,824 (3072x4096)
    unsigned short* xn    = (unsigned short*)(ws + 25427968);  //   5,898,240
    unsigned short* bqkvT = (unsigned short*)(ws + 31326208);  //  29,491,200
    unsigned short* P1    = (unsigned short*)(ws + 60817408);  //  31,457,280 (Z1 slices)
    unsigned short* attnb = (unsigned short*)(ws + 25427968);  //   8,388,608 (aliases
                                                               //   xn+bqkvT, both dead
                                                               //   before attn writes)
    unsigned short* P2    = (unsigned short*)(ws + 60817408);  //  29,491,200 (Z2=5 slices;
                                                               //   aliases P1, dead
                                                               //   before GEMM2 runs)
    // high-water: 92,274,688 B

    prep_kernel<<<7824, 256, 0, stream>>>(
        w_qkv, w_out, hidden, norm_scale, positions, bqkvT, boutT, xn, tabc, tabs);
    gemm256_kernel<20><<<4 * 20 * Z1, 512, 0, stream>>>(
        xn, bqkvT, P1, T_SEQ, QKV_N, HIDD, KS1);
    attn_kernel<<<dim3(T_SEQ / 16, NKVH), 512, 0, stream>>>(
        P1, b_qkv, sinks, tabc, tabs, attnb);
    gemm256_kernel<12><<<4 * 12 * Z2, 512, 0, stream>>>(
        attnb, boutT, P2, T_SEQ, HIDD, QDIM, KS2);
    reduce_out_kernel<<<2880, 256, 0, stream>>>(P2, b_out, hidden, out);
}